// Round 11
// baseline (180.091 us; speedup 1.0000x reference)
//
#include <hip/hip_runtime.h>

#define NB 32768
#define NCH 8
#define ROWS 16  // rows per block -> 2048 blocks, 256 thr; LDS 52KB -> 3 blocks/CU

#define WAITV8 asm volatile("s_waitcnt vmcnt(8)" ::: "memory")
#define WAITV4 asm volatile("s_waitcnt vmcnt(4)" ::: "memory")
#define WAITV0 asm volatile("s_waitcnt vmcnt(0)" ::: "memory")
#define WAITL0 asm volatile("s_waitcnt lgkmcnt(0)" ::: "memory")
#define MEMFENCE asm volatile("" ::: "memory")

typedef __bf16 bf16x8 __attribute__((ext_vector_type(8)));
typedef float f32x4 __attribute__((ext_vector_type(4)));
typedef unsigned int u32;
typedef unsigned short u16;
typedef u32 u32x4v __attribute__((ext_vector_type(4)));
typedef u32 u32x2v __attribute__((ext_vector_type(2)));

// bf16 weights, transposed to [n][k]. Order: 0=Wi 1=Wf 2=Wo 3=Wu 4=Ui 5=Uf 6=Uo 7=Uu
__device__ __align__(16) u16 g_wt[8 * 128 * 128];

__device__ __forceinline__ u16 f2bf(float f) {
  u32 u = __builtin_bit_cast(u32, f);
  u32 r = u + 0x7FFFu + ((u >> 16) & 1u);  // RNE
  return (u16)(r >> 16);
}
__device__ __forceinline__ float sigm(float s) {
  return __builtin_amdgcn_rcpf(1.0f + __expf(-s));
}
__device__ __forceinline__ float tanh_f(float v) {
  float e = __expf(2.0f * v);
  return 1.0f - 2.0f * __builtin_amdgcn_rcpf(e + 1.0f);
}

__global__ void prep_weights(const float* __restrict__ Wi, const float* __restrict__ Wf,
                             const float* __restrict__ Wo, const float* __restrict__ Wu,
                             const float* __restrict__ Ui, const float* __restrict__ Uf,
                             const float* __restrict__ Uo, const float* __restrict__ Uu) {
  __shared__ float t[128][129];
  const float* srcs[8] = {Wi, Wf, Wo, Wu, Ui, Uf, Uo, Uu};
  const float* s = srcs[blockIdx.x];
  for (int i = threadIdx.x; i < 16384; i += 256) t[i >> 7][i & 127] = s[i];
  __syncthreads();
  u16* dst = g_wt + blockIdx.x * 16384;
  for (int i = threadIdx.x; i < 16384; i += 256) {
    int n = i >> 7, k = i & 127;
    dst[i] = f2bf(t[k][n]);
  }
}

// ---------- bf16 swizzled tile (x, h_tilde) ----------
__device__ __forceinline__ bf16x8 ldA(const u32x4v* buf, int row, int ks, int g) {
  u32x4v v = buf[row * 16 + ((ks * 4 + g) ^ (row & 7))];
  return __builtin_bit_cast(bf16x8, v);
}
__device__ __forceinline__ bf16x8 ldB(const u16* wt, int col, int ks, int g) {
  return __builtin_bit_cast(bf16x8, *(const u32x4v*)(wt + col * 128 + ks * 32 + g * 8));
}

__device__ __forceinline__ void stage_load16(const float* __restrict__ src, int tid,
                                             f32x4 v[2]) {
#pragma unroll
  for (int i = 0; i < 2; ++i) {
    int q = tid + (i << 8);
    v[i] = *(const f32x4*)(src + (q >> 5) * 128 + (q & 31) * 4);
  }
}
__device__ __forceinline__ void stage_write16(u32x4v* buf, int tid, const f32x4 v[2]) {
  u32x2v* b2 = (u32x2v*)buf;
#pragma unroll
  for (int i = 0; i < 2; ++i) {
    int q = tid + (i << 8);
    int r = q >> 5, c4 = q & 31;
    u32x2v p;
    p[0] = (u32)f2bf(v[i][0]) | ((u32)f2bf(v[i][1]) << 16);
    p[1] = (u32)f2bf(v[i][2]) | ((u32)f2bf(v[i][3]) << 16);
    b2[r * 32 + (c4 ^ ((r & 7) << 1))] = p;
  }
}

// ---------- f32 tiles staged by global_load_lds (1KB coalesced per instr) ----------
// h variant: LDS 16B-block (row,pb) holds global block pb ^ (row&7)
__device__ __forceinline__ void stage_gll_swz(const float* __restrict__ src, float* dst,
                                              int lane, int wv) {
#pragma unroll
  for (int i = 0; i < 2; ++i) {
    int r0 = wv * 4 + i * 2;
    int row = r0 + (lane >> 5);
    const float* g = src + row * 128 + (((lane & 31) ^ (row & 7)) << 2);
    __builtin_amdgcn_global_load_lds(
        (const __attribute__((address_space(1))) void*)g,
        (__attribute__((address_space(3))) void*)(dst + r0 * 128), 16, 0, 0);
  }
}
// C variant: LDS block (row,pb) holds global block pb ^ (((row>>2)&3)<<2)
__device__ __forceinline__ void stage_gll_csw(const float* __restrict__ src, float* dst,
                                              int lane, int wv) {
#pragma unroll
  for (int i = 0; i < 2; ++i) {
    int r0 = wv * 4 + i * 2;
    int row = r0 + (lane >> 5);
    const float* g = src + row * 128 + (((lane & 31) ^ (((row >> 2) & 3) << 2)) << 2);
    __builtin_amdgcn_global_load_lds(
        (const __attribute__((address_space(1))) void*)g,
        (__attribute__((address_space(3))) void*)(dst + r0 * 128), 16, 0, 0);
  }
}
// A-fragment from f32 swizzled h tile, cvt to bf16 on read
__device__ __forceinline__ bf16x8 ldAf(const float* buf, int row, int ks, int g) {
  int s = row & 7;
  const float* base = buf + row * 128 + ks * 32;
  f32x4 lo = *(const f32x4*)(base + (((g * 2) ^ s) << 2));
  f32x4 hi = *(const f32x4*)(base + (((g * 2 + 1) ^ s) << 2));
  bf16x8 r;
  r[0] = (__bf16)lo[0]; r[1] = (__bf16)lo[1]; r[2] = (__bf16)lo[2]; r[3] = (__bf16)lo[3];
  r[4] = (__bf16)hi[0]; r[5] = (__bf16)hi[1]; r[6] = (__bf16)hi[2]; r[7] = (__bf16)hi[3];
  return r;
}

// acc[2] += A(16x128 bf16 LDS) @ B(128 x 32 cols of Wt)
__device__ __forceinline__ void gemm_g16(const u32x4v* a, const u16* wt, int cl, int g,
                                         int cb, f32x4 acc[2]) {
#pragma unroll
  for (int ks = 0; ks < 4; ++ks) {
    bf16x8 b0 = ldB(wt, cb + cl, ks, g);
    bf16x8 b1 = ldB(wt, cb + 16 + cl, ks, g);
    bf16x8 a0 = ldA(a, cl, ks, g);
    acc[0] = __builtin_amdgcn_mfma_f32_16x16x32_bf16(a0, b0, acc[0], 0, 0, 0);
    acc[1] = __builtin_amdgcn_mfma_f32_16x16x32_bf16(a0, b1, acc[1], 0, 0, 0);
  }
}

// fex exchange (epilogue only)
__device__ __forceinline__ int fxsw(int row, int dw) {
  int k = (row >> 2) & 3;
  return row * 128 + (dw ^ (((k & 1) << 4) | ((k >> 1) << 2)));
}
__device__ __forceinline__ void exch16(float* ex, const f32x4 fr[2], int g, int cl,
                                       int cb, int tid, f32x4 s4[2]) {
  __syncthreads();
#pragma unroll
  for (int nf = 0; nf < 2; ++nf) {
    int col = cb + nf * 16 + cl;
#pragma unroll
    for (int r_ = 0; r_ < 4; ++r_)
      ex[fxsw(g * 4 + r_, col)] = fr[nf][r_];
  }
  __syncthreads();
  int sr = tid >> 5, sc = (tid & 31) * 4;
#pragma unroll
  for (int i = 0; i < 2; ++i)
    s4[i] = *(const f32x4*)(ex + fxsw(sr + i * 8, sc));
}

__global__ __launch_bounds__(256) void tree_lstm(
    const float* __restrict__ x, const float* __restrict__ h, const float* __restrict__ C,
    const float* __restrict__ b_i, const float* __restrict__ b_f,
    const float* __restrict__ b_o, const float* __restrict__ b_u,
    float* __restrict__ out) {
  __shared__ float hbf[3][ROWS * 128];  // 24KB h triple buffer (swizzled f32)
  __shared__ float cbf[3][ROWS * 128];  // 24KB C triple buffer (col-swizzled f32)
  __shared__ u32x4v xs[ROWS * 16];      // 4KB bf16 swizzled x tile

  const int tid = threadIdx.x;
  const int lane = tid & 63;
  const int wv = tid >> 6;
  const int cb = wv * 32;
  const int row0 = blockIdx.x * ROWS;
  const int g = lane >> 4;
  const int cl = lane & 15;
  const int sr = tid >> 5;
  const int sc = (tid & 31) * 4;
  const f32x4 fz = {0.f, 0.f, 0.f, 0.f};

  // ---- prologue ----
  f32x4 xv[2];
  stage_load16(x + (size_t)row0 * 128, tid, xv);
  const float bf0 = b_f[cb + cl], bf1 = b_f[cb + 16 + cl];
  const float bi0 = b_i[cb + cl], bi1 = b_i[cb + 16 + cl];
  const float bo0 = b_o[cb + cl], bo1 = b_o[cb + 16 + cl];
  const float bu0 = b_u[cb + cl], bu1 = b_u[cb + 16 + cl];

  stage_write16(xs, tid, xv);
  __syncthreads();  // xs visible; all prologue reg-loads drained (vmcnt=0)

  // Uf B-fragments resident; afx = x@Wf (their loads drain via use-waits)
  bf16x8 uf0[4], uf1[4];
#pragma unroll
  for (int ks = 0; ks < 4; ++ks) {
    uf0[ks] = ldB(g_wt + 5 * 16384, cb + cl, ks, g);
    uf1[ks] = ldB(g_wt + 5 * 16384, cb + 16 + cl, ks, g);
  }
  f32x4 afx[2] = {fz, fz};
  gemm_g16(xs, g_wt + 1 * 16384, cl, g, cb, afx);
  __builtin_amdgcn_sched_barrier(0);

  // stage children 0..2 (12 glls outstanding entering the loop)
#pragma unroll
  for (int k = 0; k < 3; ++k) {
    stage_gll_swz(h + ((size_t)k * NB + row0) * 128, hbf[k], lane, wv);
    stage_gll_csw(C + ((size_t)k * NB + row0) * 128, cbf[k], lane, wv);
  }
  __builtin_amdgcn_sched_barrier(0);

  f32x4 accc[2] = {fz, fz};
  f32x4 htacc[2] = {fz, fz};

  // ---- child loop: counted vmcnt, never drained to 0 until the tail ----
#pragma unroll
  for (int n = 0; n < NCH; ++n) {
    // my child-n glls done (8 newest = children n+1, n+2 may stay in flight)
    if (n <= 5) { WAITV8; } else if (n == 6) { WAITV4; } else { WAITV0; }
    __builtin_amdgcn_s_barrier();  // all waves' child-n data in LDS
    MEMFENCE;

    const float* hcur = hbf[n % 3];
    f32x4 f[2] = {afx[0], afx[1]};
#pragma unroll
    for (int ks = 0; ks < 4; ++ks) {
      bf16x8 a0 = ldAf(hcur, cl, ks, g);
      f[0] = __builtin_amdgcn_mfma_f32_16x16x32_bf16(a0, uf0[ks], f[0], 0, 0, 0);
      f[1] = __builtin_amdgcn_mfma_f32_16x16x32_bf16(a0, uf1[ks], f[1], 0, 0, 0);
    }

    // h_tilde partials
#pragma unroll
    for (int i = 0; i < 2; ++i) {
      int q = tid + (i << 8);
      int r = q >> 5, c4 = q & 31;
      htacc[i] += *(const f32x4*)(hcur + r * 128 + ((c4 ^ (r & 7)) << 2));
    }

    // f-gate epilogue from swizzled C LDS
    const float* ccur = cbf[n % 3];
#pragma unroll
    for (int nf = 0; nf < 2; ++nf) {
      float bfv = nf ? bf1 : bf0;
      int lc = (cb + nf * 16 + cl) ^ (g << 4);
#pragma unroll
      for (int r = 0; r < 4; ++r)
        accc[nf][r] += sigm(f[nf][r] + bfv) * ccur[(g * 4 + r) * 128 + lc];
    }

    WAITL0;                        // my LDS reads of buffer n retired
    __builtin_amdgcn_s_barrier();  // everyone's reads done -> buffer n free
    MEMFENCE;
    if (n + 3 < NCH) {             // refill freed buffer with child n+3
      stage_gll_swz(h + ((size_t)(n + 3) * NB + row0) * 128, hbf[n % 3], lane, wv);
      stage_gll_csw(C + ((size_t)(n + 3) * NB + row0) * 128, cbf[n % 3], lane, wv);
    }
  }

  // ---- h_tilde -> bf16 swizzled tile in hbf[0] (vmcnt=0 here) ----
  stage_write16((u32x4v*)hbf[0], tid, htacc);
  __syncthreads();
  const u32x4v* ht = (const u32x4v*)hbf[0];
  float* ex = cbf[0];

  f32x4 pre[2], s4[2];

  // u = tanh(x@Wu + ht@Uu + bu)
  pre[0] = fz; pre[1] = fz;
  gemm_g16(xs, g_wt + 3 * 16384, cl, g, cb, pre);
  gemm_g16(ht, g_wt + 7 * 16384, cl, g, cb, pre);
  f32x4 uF[2];
#pragma unroll
  for (int nf = 0; nf < 2; ++nf) {
    float bv = nf ? bu1 : bu0;
#pragma unroll
    for (int r = 0; r < 4; ++r) uF[nf][r] = tanh_f(pre[nf][r] + bv);
  }

  // i gate -> c = i*u + accc
  pre[0] = fz; pre[1] = fz;
  gemm_g16(xs, g_wt + 0 * 16384, cl, g, cb, pre);
  gemm_g16(ht, g_wt + 4 * 16384, cl, g, cb, pre);
  f32x4 cF[2], tF[2];
#pragma unroll
  for (int nf = 0; nf < 2; ++nf) {
    float bv = nf ? bi1 : bi0;
#pragma unroll
    for (int r = 0; r < 4; ++r) {
      float cv = sigm(pre[nf][r] + bv) * uF[nf][r] + accc[nf][r];
      cF[nf][r] = cv;
      tF[nf][r] = tanh_f(cv);
    }
  }
  exch16(ex, cF, g, cl, cb, tid, s4);
  float* outc = out + (size_t)NB * 128;
#pragma unroll
  for (int i = 0; i < 2; ++i)
    *(f32x4*)(outc + (size_t)(row0 + sr + i * 8) * 128 + sc) = s4[i];

  // o gate -> h_j
  pre[0] = fz; pre[1] = fz;
  gemm_g16(xs, g_wt + 2 * 16384, cl, g, cb, pre);
  gemm_g16(ht, g_wt + 6 * 16384, cl, g, cb, pre);
  f32x4 hF[2];
#pragma unroll
  for (int nf = 0; nf < 2; ++nf) {
    float bv = nf ? bo1 : bo0;
#pragma unroll
    for (int r = 0; r < 4; ++r)
      hF[nf][r] = sigm(pre[nf][r] + bv) * tF[nf][r];
  }
  exch16(ex, hF, g, cl, cb, tid, s4);
#pragma unroll
  for (int i = 0; i < 2; ++i)
    *(f32x4*)(out + (size_t)(row0 + sr + i * 8) * 128 + sc) = s4[i];
}

extern "C" void kernel_launch(void* const* d_in, const int* in_sizes, int n_in,
                              void* d_out, int out_size, void* d_ws, size_t ws_size,
                              hipStream_t stream) {
  (void)in_sizes; (void)n_in; (void)out_size; (void)d_ws; (void)ws_size;
  const float* x = (const float*)d_in[0];
  const float* h = (const float*)d_in[1];
  const float* C = (const float*)d_in[2];

  prep_weights<<<8, 256, 0, stream>>>(
      (const float*)d_in[3], (const float*)d_in[4], (const float*)d_in[5],
      (const float*)d_in[6], (const float*)d_in[7], (const float*)d_in[8],
      (const float*)d_in[9], (const float*)d_in[10]);

  tree_lstm<<<NB / ROWS, 256, 0, stream>>>(
      x, h, C,
      (const float*)d_in[11], (const float*)d_in[12],
      (const float*)d_in[13], (const float*)d_in[14],
      (float*)d_out);
}

// Round 12
// 110.564 us; speedup vs baseline: 1.6288x; 1.6288x over previous
//
#include <hip/hip_runtime.h>

#define NB 32768
#define NCH 8
#define ROWS 32  // rows per block -> 1024 blocks, 256 thr; LDS 72KB -> 2 blocks/CU

#define WAITV8 asm volatile("s_waitcnt vmcnt(8)" ::: "memory")
#define WAITV0 asm volatile("s_waitcnt vmcnt(0)" ::: "memory")
#define WAITL0 asm volatile("s_waitcnt lgkmcnt(0)" ::: "memory")

typedef __bf16 bf16x8 __attribute__((ext_vector_type(8)));
typedef float f32x4 __attribute__((ext_vector_type(4)));
typedef unsigned int u32;
typedef unsigned short u16;
typedef u32 u32x4v __attribute__((ext_vector_type(4)));
typedef u32 u32x2v __attribute__((ext_vector_type(2)));

// bf16 weights, transposed to [n][k]. Order: 0=Wi 1=Wf 2=Wo 3=Wu 4=Ui 5=Uf 6=Uo 7=Uu
__device__ __align__(16) u16 g_wt[8 * 128 * 128];

__device__ __forceinline__ u16 f2bf(float f) {
  u32 u = __builtin_bit_cast(u32, f);
  u32 r = u + 0x7FFFu + ((u >> 16) & 1u);  // RNE
  return (u16)(r >> 16);
}
__device__ __forceinline__ float sigm(float s) {
  return __builtin_amdgcn_rcpf(1.0f + __expf(-s));
}
__device__ __forceinline__ float tanh_f(float v) {
  float e = __expf(2.0f * v);
  return 1.0f - 2.0f * __builtin_amdgcn_rcpf(e + 1.0f);
}

__global__ void prep_weights(const float* __restrict__ Wi, const float* __restrict__ Wf,
                             const float* __restrict__ Wo, const float* __restrict__ Wu,
                             const float* __restrict__ Ui, const float* __restrict__ Uf,
                             const float* __restrict__ Uo, const float* __restrict__ Uu) {
  __shared__ float t[128][129];
  const float* srcs[8] = {Wi, Wf, Wo, Wu, Ui, Uf, Uo, Uu};
  const float* s = srcs[blockIdx.x];
  for (int i = threadIdx.x; i < 16384; i += 256) t[i >> 7][i & 127] = s[i];
  __syncthreads();
  u16* dst = g_wt + blockIdx.x * 16384;
  for (int i = threadIdx.x; i < 16384; i += 256) {
    int n = i >> 7, k = i & 127;
    dst[i] = f2bf(t[k][n]);
  }
}

// ---------- bf16 swizzled tile (x, h_tilde) ----------
__device__ __forceinline__ bf16x8 ldA(const u32x4v* buf, int row, int ks, int g) {
  u32x4v v = buf[row * 16 + ((ks * 4 + g) ^ (row & 7))];
  return __builtin_bit_cast(bf16x8, v);
}
__device__ __forceinline__ bf16x8 ldB(const u16* wt, int col, int ks, int g) {
  return __builtin_bit_cast(bf16x8, *(const u32x4v*)(wt + col * 128 + ks * 32 + g * 8));
}

__device__ __forceinline__ void stage_load(const float* __restrict__ src, int tid, f32x4 v[4]) {
#pragma unroll
  for (int i = 0; i < 4; ++i) {
    int q = tid + (i << 8);
    v[i] = *(const f32x4*)(src + (q >> 5) * 128 + (q & 31) * 4);
  }
}
__device__ __forceinline__ void stage_write(u32x4v* buf, int tid, const f32x4 v[4]) {
  u32x2v* b2 = (u32x2v*)buf;
#pragma unroll
  for (int i = 0; i < 4; ++i) {
    int q = tid + (i << 8);
    int r = q >> 5, c4 = q & 31;
    u32x2v p;
    p[0] = (u32)f2bf(v[i][0]) | ((u32)f2bf(v[i][1]) << 16);
    p[1] = (u32)f2bf(v[i][2]) | ((u32)f2bf(v[i][3]) << 16);
    b2[r * 32 + (c4 ^ ((r & 7) << 1))] = p;
  }
}

// ---------- f32 tiles staged by global_load_lds (1KB coalesced per instr) ----------
// h variant: LDS 16B-block (row,pb) holds global block pb ^ (row&7)
__device__ __forceinline__ void stage_gll_swz(const float* __restrict__ src, float* dst,
                                              int lane, int wv) {
#pragma unroll
  for (int i = 0; i < 4; ++i) {
    int r0 = wv * 8 + i * 2;
    int row = r0 + (lane >> 5);
    const float* g = src + row * 128 + (((lane & 31) ^ (row & 7)) << 2);
    __builtin_amdgcn_global_load_lds(
        (const __attribute__((address_space(1))) void*)g,
        (__attribute__((address_space(3))) void*)(dst + r0 * 128), 16, 0, 0);
  }
}
// C variant: LDS block (row,pb) holds global block pb ^ (((row>>2)&3)<<2)
// -> frag readback dword col ^ (g<<4): 2-way banked (free)
__device__ __forceinline__ void stage_gll_csw(const float* __restrict__ src, float* dst,
                                              int lane, int wv) {
#pragma unroll
  for (int i = 0; i < 4; ++i) {
    int r0 = wv * 8 + i * 2;
    int row = r0 + (lane >> 5);
    const float* g = src + row * 128 + (((lane & 31) ^ (((row >> 2) & 3) << 2)) << 2);
    __builtin_amdgcn_global_load_lds(
        (const __attribute__((address_space(1))) void*)g,
        (__attribute__((address_space(3))) void*)(dst + r0 * 128), 16, 0, 0);
  }
}
// A-fragment from f32 swizzled h tile, cvt to bf16 on read
__device__ __forceinline__ bf16x8 ldAf(const float* buf, int row, int ks, int g) {
  int s = row & 7;
  const float* base = buf + row * 128 + ks * 32;
  f32x4 lo = *(const f32x4*)(base + (((g * 2) ^ s) << 2));
  f32x4 hi = *(const f32x4*)(base + (((g * 2 + 1) ^ s) << 2));
  bf16x8 r;
  r[0] = (__bf16)lo[0]; r[1] = (__bf16)lo[1]; r[2] = (__bf16)lo[2]; r[3] = (__bf16)lo[3];
  r[4] = (__bf16)hi[0]; r[5] = (__bf16)hi[1]; r[6] = (__bf16)hi[2]; r[7] = (__bf16)hi[3];
  return r;
}

// acc[2][2] += A(32x128 bf16 LDS) @ B(128 x 32 cols of Wt)  (epilogue path)
__device__ __forceinline__ void gemm_g(const u32x4v* a, const u16* wt, int cl, int g,
                                       int cb, f32x4 acc[2][2]) {
#pragma unroll
  for (int ks = 0; ks < 4; ++ks) {
    bf16x8 b0 = ldB(wt, cb + cl, ks, g);
    bf16x8 b1 = ldB(wt, cb + 16 + cl, ks, g);
    bf16x8 a0 = ldA(a, cl, ks, g);
    bf16x8 a1 = ldA(a, 16 + cl, ks, g);
    acc[0][0] = __builtin_amdgcn_mfma_f32_16x16x32_bf16(a0, b0, acc[0][0], 0, 0, 0);
    acc[0][1] = __builtin_amdgcn_mfma_f32_16x16x32_bf16(a0, b1, acc[0][1], 0, 0, 0);
    acc[1][0] = __builtin_amdgcn_mfma_f32_16x16x32_bf16(a1, b0, acc[1][0], 0, 0, 0);
    acc[1][1] = __builtin_amdgcn_mfma_f32_16x16x32_bf16(a1, b1, acc[1][1], 0, 0, 0);
  }
}

// fex exchange (epilogue only)
__device__ __forceinline__ int fxsw(int row, int dw) {
  int k = (row >> 2) & 3;
  return row * 128 + (dw ^ (((k & 1) << 4) | ((k >> 1) << 2)));
}
__device__ __forceinline__ void exch(float* ex, const f32x4 fr[2][2], int g, int cl,
                                     int cb, int tid, f32x4 s4[4]) {
  __syncthreads();
#pragma unroll
  for (int m = 0; m < 2; ++m)
#pragma unroll
    for (int nf = 0; nf < 2; ++nf) {
      int col = cb + nf * 16 + cl;
#pragma unroll
      for (int r_ = 0; r_ < 4; ++r_)
        ex[fxsw(m * 16 + g * 4 + r_, col)] = fr[m][nf][r_];
    }
  __syncthreads();
  int sr = tid >> 5, sc = (tid & 31) * 4;
#pragma unroll
  for (int i = 0; i < 4; ++i)
    s4[i] = *(const f32x4*)(ex + fxsw(sr + i * 8, sc));
}

__global__ __launch_bounds__(256) void tree_lstm(
    const float* __restrict__ x, const float* __restrict__ h, const float* __restrict__ C,
    const float* __restrict__ b_i, const float* __restrict__ b_f,
    const float* __restrict__ b_o, const float* __restrict__ b_u,
    float* __restrict__ out) {
  __shared__ float hbf[2][ROWS * 128];  // 32KB h double buffer (swizzled f32)
  __shared__ float cbf[2][ROWS * 128];  // 32KB C double buffer (col-swizzled f32)
  __shared__ u32x4v xs[ROWS * 16];      // 8KB bf16 swizzled x tile

  const int tid = threadIdx.x;
  const int lane = tid & 63;
  const int wv = tid >> 6;
  const int cb = wv * 32;
  const int row0 = blockIdx.x * ROWS;
  const int g = lane >> 4;
  const int cl = lane & 15;
  const int sr = tid >> 5;
  const int sc = (tid & 31) * 4;
  const f32x4 fz = {0.f, 0.f, 0.f, 0.f};

  // ---- prologue: register-path loads first, all consumed before counted glls ----
  f32x4 xv[4];
  stage_load(x + (size_t)row0 * 128, tid, xv);
  const float bf0 = b_f[cb + cl], bf1 = b_f[cb + 16 + cl];
  const float bi0 = b_i[cb + cl], bi1 = b_i[cb + 16 + cl];
  const float bo0 = b_o[cb + cl], bo1 = b_o[cb + 16 + cl];
  const float bu0 = b_u[cb + cl], bu1 = b_u[cb + 16 + cl];

  stage_write(xs, tid, xv);
  __syncthreads();  // xs visible

  // Uf resident; afx = x@Wf (all reg-loads consumed by MFMA waits)
  bf16x8 uf0[4], uf1[4];
#pragma unroll
  for (int ks = 0; ks < 4; ++ks) {
    uf0[ks] = ldB(g_wt + 5 * 16384, cb + cl, ks, g);
    uf1[ks] = ldB(g_wt + 5 * 16384, cb + 16 + cl, ks, g);
  }
  f32x4 afx[2][2];
#pragma unroll
  for (int m = 0; m < 2; ++m) { afx[m][0] = fz; afx[m][1] = fz; }
  gemm_g(xs, g_wt + 1 * 16384, cl, g, cb, afx);

  // clean vmcnt slate, then stage children 0 and 1 (exactly 16 glls outstanding)
  WAITV0;
  stage_gll_swz(h + (size_t)row0 * 128, hbf[0], lane, wv);
  stage_gll_csw(C + (size_t)row0 * 128, cbf[0], lane, wv);
  stage_gll_swz(h + ((size_t)NB + row0) * 128, hbf[1], lane, wv);
  stage_gll_csw(C + ((size_t)NB + row0) * 128, cbf[1], lane, wv);
  __builtin_amdgcn_sched_barrier(0);

  f32x4 accc[2][2];
#pragma unroll
  for (int m = 0; m < 2; ++m) { accc[m][0] = fz; accc[m][1] = fz; }
  f32x4 htacc[4] = {fz, fz, fz, fz};

  // ---- child loop n=0..6: counted vmcnt(8) -> child n+1..n+2 stay in flight ----
#pragma unroll 1
  for (int n = 0; n < NCH - 1; ++n) {
    WAITV8;                        // my child-n glls landed (newest 8 = child n+1 in flight)
    __builtin_amdgcn_s_barrier();  // all waves' child-n data in LDS

    const float* hcur = hbf[n & 1];
    f32x4 f[2][2];
#pragma unroll
    for (int m = 0; m < 2; ++m) { f[m][0] = afx[m][0]; f[m][1] = afx[m][1]; }
#pragma unroll
    for (int ks = 0; ks < 4; ++ks) {
      bf16x8 a0 = ldAf(hcur, cl, ks, g);
      bf16x8 a1 = ldAf(hcur, 16 + cl, ks, g);
      f[0][0] = __builtin_amdgcn_mfma_f32_16x16x32_bf16(a0, uf0[ks], f[0][0], 0, 0, 0);
      f[0][1] = __builtin_amdgcn_mfma_f32_16x16x32_bf16(a0, uf1[ks], f[0][1], 0, 0, 0);
      f[1][0] = __builtin_amdgcn_mfma_f32_16x16x32_bf16(a1, uf0[ks], f[1][0], 0, 0, 0);
      f[1][1] = __builtin_amdgcn_mfma_f32_16x16x32_bf16(a1, uf1[ks], f[1][1], 0, 0, 0);
    }

    // h_tilde partials (conflict-free b128)
#pragma unroll
    for (int i = 0; i < 4; ++i) {
      int q = tid + (i << 8);
      int r = q >> 5, c4 = q & 31;
      htacc[i] += *(const f32x4*)(hcur + r * 128 + ((c4 ^ (r & 7)) << 2));
    }

    // f-gate epilogue from swizzled C LDS (2-way banked)
    const float* ccur = cbf[n & 1];
#pragma unroll
    for (int m = 0; m < 2; ++m)
#pragma unroll
      for (int nf = 0; nf < 2; ++nf) {
        float bfv = nf ? bf1 : bf0;
        int lc = (cb + nf * 16 + cl) ^ (g << 4);
#pragma unroll
        for (int r = 0; r < 4; ++r)
          accc[m][nf][r] += sigm(f[m][nf][r] + bfv) * ccur[(m * 16 + g * 4 + r) * 128 + lc];
      }

    WAITL0;                        // my LDS reads of buffer n&1 retired
    __builtin_amdgcn_s_barrier();  // all waves done reading -> buffer free
    if (n < NCH - 2) {             // refill freed buffer with child n+2
      stage_gll_swz(h + ((size_t)(n + 2) * NB + row0) * 128, hbf[n & 1], lane, wv);
      stage_gll_csw(C + ((size_t)(n + 2) * NB + row0) * 128, cbf[n & 1], lane, wv);
      __builtin_amdgcn_sched_barrier(0);
    }
  }

  // ---- peeled child 7 (buf 1): full drain ----
  {
    WAITV0;
    __builtin_amdgcn_s_barrier();
    const float* hcur = hbf[1];
    f32x4 f[2][2];
#pragma unroll
    for (int m = 0; m < 2; ++m) { f[m][0] = afx[m][0]; f[m][1] = afx[m][1]; }
#pragma unroll
    for (int ks = 0; ks < 4; ++ks) {
      bf16x8 a0 = ldAf(hcur, cl, ks, g);
      bf16x8 a1 = ldAf(hcur, 16 + cl, ks, g);
      f[0][0] = __builtin_amdgcn_mfma_f32_16x16x32_bf16(a0, uf0[ks], f[0][0], 0, 0, 0);
      f[0][1] = __builtin_amdgcn_mfma_f32_16x16x32_bf16(a0, uf1[ks], f[0][1], 0, 0, 0);
      f[1][0] = __builtin_amdgcn_mfma_f32_16x16x32_bf16(a1, uf0[ks], f[1][0], 0, 0, 0);
      f[1][1] = __builtin_amdgcn_mfma_f32_16x16x32_bf16(a1, uf1[ks], f[1][1], 0, 0, 0);
    }
#pragma unroll
    for (int i = 0; i < 4; ++i) {
      int q = tid + (i << 8);
      int r = q >> 5, c4 = q & 31;
      htacc[i] += *(const f32x4*)(hcur + r * 128 + ((c4 ^ (r & 7)) << 2));
    }
    const float* ccur = cbf[1];
#pragma unroll
    for (int m = 0; m < 2; ++m)
#pragma unroll
      for (int nf = 0; nf < 2; ++nf) {
        float bfv = nf ? bf1 : bf0;
        int lc = (cb + nf * 16 + cl) ^ (g << 4);
#pragma unroll
        for (int r = 0; r < 4; ++r)
          accc[m][nf][r] += sigm(f[m][nf][r] + bfv) * ccur[(m * 16 + g * 4 + r) * 128 + lc];
      }
  }
  __syncthreads();  // all reads of hbf done before h_tilde overwrite

  // ---- h_tilde -> bf16 swizzled tile in hbf[0] ----
  {
    u32x2v* b2 = (u32x2v*)hbf[0];
#pragma unroll
    for (int i = 0; i < 4; ++i) {
      int q = tid + (i << 8);
      int r = q >> 5, c4 = q & 31;
      u32x2v p;
      p[0] = (u32)f2bf(htacc[i][0]) | ((u32)f2bf(htacc[i][1]) << 16);
      p[1] = (u32)f2bf(htacc[i][2]) | ((u32)f2bf(htacc[i][3]) << 16);
      b2[r * 32 + (c4 ^ ((r & 7) << 1))] = p;
    }
  }
  __syncthreads();
  const u32x4v* ht = (const u32x4v*)hbf[0];
  float* ex = cbf[0];

  f32x4 pre[2][2], s4[4];

  // u = tanh(x@Wu + ht@Uu + bu)
#pragma unroll
  for (int m = 0; m < 2; ++m) { pre[m][0] = fz; pre[m][1] = fz; }
  gemm_g(xs, g_wt + 3 * 16384, cl, g, cb, pre);
  gemm_g(ht, g_wt + 7 * 16384, cl, g, cb, pre);
  f32x4 uF[2][2];
#pragma unroll
  for (int m = 0; m < 2; ++m)
#pragma unroll
    for (int nf = 0; nf < 2; ++nf) {
      float bv = nf ? bu1 : bu0;
#pragma unroll
      for (int r = 0; r < 4; ++r) uF[m][nf][r] = tanh_f(pre[m][nf][r] + bv);
    }

  // i gate -> c = i*u + accc
#pragma unroll
  for (int m = 0; m < 2; ++m) { pre[m][0] = fz; pre[m][1] = fz; }
  gemm_g(xs, g_wt + 0 * 16384, cl, g, cb, pre);
  gemm_g(ht, g_wt + 4 * 16384, cl, g, cb, pre);
  f32x4 cF[2][2], tF[2][2];
#pragma unroll
  for (int m = 0; m < 2; ++m)
#pragma unroll
    for (int nf = 0; nf < 2; ++nf) {
      float bv = nf ? bi1 : bi0;
#pragma unroll
      for (int r = 0; r < 4; ++r) {
        float cv = sigm(pre[m][nf][r] + bv) * uF[m][nf][r] + accc[m][nf][r];
        cF[m][nf][r] = cv;
        tF[m][nf][r] = tanh_f(cv);
      }
    }
  exch(ex, cF, g, cl, cb, tid, s4);
  float* outc = out + (size_t)NB * 128;
#pragma unroll
  for (int i = 0; i < 4; ++i)
    *(f32x4*)(outc + (size_t)(row0 + sr + i * 8) * 128 + sc) = s4[i];

  // o gate -> h_j
#pragma unroll
  for (int m = 0; m < 2; ++m) { pre[m][0] = fz; pre[m][1] = fz; }
  gemm_g(xs, g_wt + 2 * 16384, cl, g, cb, pre);
  gemm_g(ht, g_wt + 6 * 16384, cl, g, cb, pre);
  f32x4 hF[2][2];
#pragma unroll
  for (int m = 0; m < 2; ++m)
#pragma unroll
    for (int nf = 0; nf < 2; ++nf) {
      float bv = nf ? bo1 : bo0;
#pragma unroll
      for (int r = 0; r < 4; ++r)
        hF[m][nf][r] = sigm(pre[m][nf][r] + bv) * tF[m][nf][r];
    }
  exch(ex, hF, g, cl, cb, tid, s4);
#pragma unroll
  for (int i = 0; i < 4; ++i)
    *(f32x4*)(out + (size_t)(row0 + sr + i * 8) * 128 + sc) = s4[i];
}

extern "C" void kernel_launch(void* const* d_in, const int* in_sizes, int n_in,
                              void* d_out, int out_size, void* d_ws, size_t ws_size,
                              hipStream_t stream) {
  (void)in_sizes; (void)n_in; (void)out_size; (void)d_ws; (void)ws_size;
  const float* x = (const float*)d_in[0];
  const float* h = (const float*)d_in[1];
  const float* C = (const float*)d_in[2];

  prep_weights<<<8, 256, 0, stream>>>(
      (const float*)d_in[3], (const float*)d_in[4], (const float*)d_in[5],
      (const float*)d_in[6], (const float*)d_in[7], (const float*)d_in[8],
      (const float*)d_in[9], (const float*)d_in[10]);

  tree_lstm<<<NB / ROWS, 256, 0, stream>>>(
      x, h, C,
      (const float*)d_in[11], (const float*)d_in[12],
      (const float*)d_in[13], (const float*)d_in[14],
      (float*)d_out);
}

// Round 13
// 108.191 us; speedup vs baseline: 1.6646x; 1.0219x over previous
//
#include <hip/hip_runtime.h>

#define NB 32768
#define NCH 8
#define ROWS 32  // rows per block -> 1024 blocks, 256 thr; LDS 72KB -> 2 blocks/CU

#define WAITL0 asm volatile("s_waitcnt lgkmcnt(0)" ::: "memory")

typedef __bf16 bf16x8 __attribute__((ext_vector_type(8)));
typedef float f32x4 __attribute__((ext_vector_type(4)));
typedef unsigned int u32;
typedef unsigned short u16;
typedef u32 u32x4v __attribute__((ext_vector_type(4)));
typedef u32 u32x2v __attribute__((ext_vector_type(2)));

// bf16 weights, transposed to [n][k]. Order: 0=Wi 1=Wf 2=Wo 3=Wu 4=Ui 5=Uf 6=Uo 7=Uu
__device__ __align__(16) u16 g_wt[8 * 128 * 128];

__device__ __forceinline__ u16 f2bf(float f) {
  u32 u = __builtin_bit_cast(u32, f);
  u32 r = u + 0x7FFFu + ((u >> 16) & 1u);  // RNE
  return (u16)(r >> 16);
}
__device__ __forceinline__ float sigm(float s) {
  return __builtin_amdgcn_rcpf(1.0f + __expf(-s));
}
__device__ __forceinline__ float tanh_f(float v) {
  float e = __expf(2.0f * v);
  return 1.0f - 2.0f * __builtin_amdgcn_rcpf(e + 1.0f);
}

__global__ void prep_weights(const float* __restrict__ Wi, const float* __restrict__ Wf,
                             const float* __restrict__ Wo, const float* __restrict__ Wu,
                             const float* __restrict__ Ui, const float* __restrict__ Uf,
                             const float* __restrict__ Uo, const float* __restrict__ Uu) {
  __shared__ float t[128][129];
  const float* srcs[8] = {Wi, Wf, Wo, Wu, Ui, Uf, Uo, Uu};
  const float* s = srcs[blockIdx.x];
  for (int i = threadIdx.x; i < 16384; i += 256) t[i >> 7][i & 127] = s[i];
  __syncthreads();
  u16* dst = g_wt + blockIdx.x * 16384;
  for (int i = threadIdx.x; i < 16384; i += 256) {
    int n = i >> 7, k = i & 127;
    dst[i] = f2bf(t[k][n]);
  }
}

// ---------- bf16 swizzled tile (x, h_tilde) ----------
__device__ __forceinline__ bf16x8 ldA(const u32x4v* buf, int row, int ks, int g) {
  u32x4v v = buf[row * 16 + ((ks * 4 + g) ^ (row & 7))];
  return __builtin_bit_cast(bf16x8, v);
}
__device__ __forceinline__ bf16x8 ldB(const u16* wt, int col, int ks, int g) {
  return __builtin_bit_cast(bf16x8, *(const u32x4v*)(wt + col * 128 + ks * 32 + g * 8));
}

// staging layout: thread owns rows (tid>>5)+i*8, dwords (tid&31)*4..+3
__device__ __forceinline__ void stage_load(const float* __restrict__ src, int tid, f32x4 v[4]) {
#pragma unroll
  for (int i = 0; i < 4; ++i) {
    int q = tid + (i << 8);
    v[i] = *(const f32x4*)(src + (q >> 5) * 128 + (q & 31) * 4);
  }
}
__device__ __forceinline__ void stage_write(u32x4v* buf, int tid, const f32x4 v[4]) {
  u32x2v* b2 = (u32x2v*)buf;
#pragma unroll
  for (int i = 0; i < 4; ++i) {
    int q = tid + (i << 8);
    int r = q >> 5, c4 = q & 31;
    u32x2v p;
    p[0] = (u32)f2bf(v[i][0]) | ((u32)f2bf(v[i][1]) << 16);
    p[1] = (u32)f2bf(v[i][2]) | ((u32)f2bf(v[i][3]) << 16);
    b2[r * 32 + (c4 ^ ((r & 7) << 1))] = p;
  }
}

// commit reg-staged child to LDS: h swizzled (^(r&7) on 16B blocks),
// C col-swizzled (^(((r>>2)&3)<<2)); also accumulate h_tilde (exact f32, free).
__device__ __forceinline__ void commit_tiles(float* hdst, float* cdst, int tid,
                                             const f32x4 hv[4], const f32x4 cv[4],
                                             f32x4 htacc[4]) {
#pragma unroll
  for (int i = 0; i < 4; ++i) {
    int q = tid + (i << 8);
    int r = q >> 5, c4 = q & 31;
    htacc[i] += hv[i];
    *(f32x4*)(hdst + r * 128 + ((c4 ^ (r & 7)) << 2)) = hv[i];
    *(f32x4*)(cdst + r * 128 + ((c4 ^ (((r >> 2) & 3) << 2)) << 2)) = cv[i];
  }
}

// A-fragment from f32 swizzled h tile, cvt to bf16 on read
__device__ __forceinline__ bf16x8 ldAf(const float* buf, int row, int ks, int g) {
  int s = row & 7;
  const float* base = buf + row * 128 + ks * 32;
  f32x4 lo = *(const f32x4*)(base + (((g * 2) ^ s) << 2));
  f32x4 hi = *(const f32x4*)(base + (((g * 2 + 1) ^ s) << 2));
  bf16x8 r;
  r[0] = (__bf16)lo[0]; r[1] = (__bf16)lo[1]; r[2] = (__bf16)lo[2]; r[3] = (__bf16)lo[3];
  r[4] = (__bf16)hi[0]; r[5] = (__bf16)hi[1]; r[6] = (__bf16)hi[2]; r[7] = (__bf16)hi[3];
  return r;
}

// acc[2][2] += A(32x128 bf16 LDS) @ B(128 x 32 cols of Wt)  (epilogue path)
__device__ __forceinline__ void gemm_g(const u32x4v* a, const u16* wt, int cl, int g,
                                       int cb, f32x4 acc[2][2]) {
#pragma unroll
  for (int ks = 0; ks < 4; ++ks) {
    bf16x8 b0 = ldB(wt, cb + cl, ks, g);
    bf16x8 b1 = ldB(wt, cb + 16 + cl, ks, g);
    bf16x8 a0 = ldA(a, cl, ks, g);
    bf16x8 a1 = ldA(a, 16 + cl, ks, g);
    acc[0][0] = __builtin_amdgcn_mfma_f32_16x16x32_bf16(a0, b0, acc[0][0], 0, 0, 0);
    acc[0][1] = __builtin_amdgcn_mfma_f32_16x16x32_bf16(a0, b1, acc[0][1], 0, 0, 0);
    acc[1][0] = __builtin_amdgcn_mfma_f32_16x16x32_bf16(a1, b0, acc[1][0], 0, 0, 0);
    acc[1][1] = __builtin_amdgcn_mfma_f32_16x16x32_bf16(a1, b1, acc[1][1], 0, 0, 0);
  }
}

// fex exchange (epilogue only)
__device__ __forceinline__ int fxsw(int row, int dw) {
  int k = (row >> 2) & 3;
  return row * 128 + (dw ^ (((k & 1) << 4) | ((k >> 1) << 2)));
}
__device__ __forceinline__ void exch(float* ex, const f32x4 fr[2][2], int g, int cl,
                                     int cb, int tid, f32x4 s4[4]) {
  __syncthreads();
#pragma unroll
  for (int m = 0; m < 2; ++m)
#pragma unroll
    for (int nf = 0; nf < 2; ++nf) {
      int col = cb + nf * 16 + cl;
#pragma unroll
      for (int r_ = 0; r_ < 4; ++r_)
        ex[fxsw(m * 16 + g * 4 + r_, col)] = fr[m][nf][r_];
    }
  __syncthreads();
  int sr = tid >> 5, sc = (tid & 31) * 4;
#pragma unroll
  for (int i = 0; i < 4; ++i)
    s4[i] = *(const f32x4*)(ex + fxsw(sr + i * 8, sc));
}

// compute one child: f-GEMM + fused f-gate epilogue (reads LDS only)
__device__ __forceinline__ void child_compute(const float* hcur, const float* ccur,
                                              const bf16x8 uf0[4], const bf16x8 uf1[4],
                                              const f32x4 afx[2][2], float bf0, float bf1,
                                              int cl, int g, int cb, f32x4 accc[2][2]) {
  f32x4 f[2][2];
#pragma unroll
  for (int m = 0; m < 2; ++m) { f[m][0] = afx[m][0]; f[m][1] = afx[m][1]; }
#pragma unroll
  for (int ks = 0; ks < 4; ++ks) {
    bf16x8 a0 = ldAf(hcur, cl, ks, g);
    bf16x8 a1 = ldAf(hcur, 16 + cl, ks, g);
    f[0][0] = __builtin_amdgcn_mfma_f32_16x16x32_bf16(a0, uf0[ks], f[0][0], 0, 0, 0);
    f[0][1] = __builtin_amdgcn_mfma_f32_16x16x32_bf16(a0, uf1[ks], f[0][1], 0, 0, 0);
    f[1][0] = __builtin_amdgcn_mfma_f32_16x16x32_bf16(a1, uf0[ks], f[1][0], 0, 0, 0);
    f[1][1] = __builtin_amdgcn_mfma_f32_16x16x32_bf16(a1, uf1[ks], f[1][1], 0, 0, 0);
  }
#pragma unroll
  for (int m = 0; m < 2; ++m)
#pragma unroll
    for (int nf = 0; nf < 2; ++nf) {
      float bfv = nf ? bf1 : bf0;
      int lc = (cb + nf * 16 + cl) ^ (g << 4);
#pragma unroll
      for (int r = 0; r < 4; ++r)
        accc[m][nf][r] += sigm(f[m][nf][r] + bfv) * ccur[(m * 16 + g * 4 + r) * 128 + lc];
    }
}

__global__ __launch_bounds__(256) void tree_lstm(
    const float* __restrict__ x, const float* __restrict__ h, const float* __restrict__ C,
    const float* __restrict__ b_i, const float* __restrict__ b_f,
    const float* __restrict__ b_o, const float* __restrict__ b_u,
    float* __restrict__ out) {
  __shared__ float hbf[2][ROWS * 128];  // 32KB h double buffer (swizzled f32)
  __shared__ float cbf[2][ROWS * 128];  // 32KB C double buffer (col-swizzled f32)
  __shared__ u32x4v xs[ROWS * 16];      // 8KB bf16 swizzled x tile

  const int tid = threadIdx.x;
  const int lane = tid & 63;
  const int wv = tid >> 6;
  const int cb = wv * 32;
  const int row0 = blockIdx.x * ROWS;
  const int g = lane >> 4;
  const int cl = lane & 15;
  const int sr = tid >> 5;
  const int sc = (tid & 31) * 4;
  const f32x4 fz = {0.f, 0.f, 0.f, 0.f};

  // ---- prologue ----
  f32x4 xv[4];
  stage_load(x + (size_t)row0 * 128, tid, xv);
  const float bf0 = b_f[cb + cl], bf1 = b_f[cb + 16 + cl];
  const float bi0 = b_i[cb + cl], bi1 = b_i[cb + 16 + cl];
  const float bo0 = b_o[cb + cl], bo1 = b_o[cb + 16 + cl];
  const float bu0 = b_u[cb + cl], bu1 = b_u[cb + 16 + cl];

  stage_write(xs, tid, xv);
  __syncthreads();  // xs visible

  // child 0 reg-loads in flight under Uf/afx compute
  f32x4 hv[4], cv[4];
  stage_load(h + (size_t)row0 * 128, tid, hv);
  stage_load(C + (size_t)row0 * 128, tid, cv);
  __builtin_amdgcn_sched_barrier(0);

  bf16x8 uf0[4], uf1[4];
#pragma unroll
  for (int ks = 0; ks < 4; ++ks) {
    uf0[ks] = ldB(g_wt + 5 * 16384, cb + cl, ks, g);
    uf1[ks] = ldB(g_wt + 5 * 16384, cb + 16 + cl, ks, g);
  }
  f32x4 afx[2][2];
#pragma unroll
  for (int m = 0; m < 2; ++m) { afx[m][0] = fz; afx[m][1] = fz; }
  gemm_g(xs, g_wt + 1 * 16384, cl, g, cb, afx);

  f32x4 accc[2][2];
#pragma unroll
  for (int m = 0; m < 2; ++m) { accc[m][0] = fz; accc[m][1] = fz; }
  f32x4 htacc[4] = {fz, fz, fz, fz};

  // commit child 0, issue child 1 (stay in flight across the barrier)
  commit_tiles(hbf[0], cbf[0], tid, hv, cv, htacc);
  stage_load(h + ((size_t)NB + row0) * 128, tid, hv);
  stage_load(C + ((size_t)NB + row0) * 128, tid, cv);
  __builtin_amdgcn_sched_barrier(0);
  WAITL0;
  __builtin_amdgcn_s_barrier();  // raw barrier: does NOT drain vmcnt

  // ---- child loop: compute n from LDS | commit n+1 | issue n+2 | barrier ----
#pragma unroll 1
  for (int n = 0; n < NCH - 1; ++n) {
    child_compute(hbf[n & 1], cbf[n & 1], uf0, uf1, afx, bf0, bf1, cl, g, cb, accc);

    // commit child n+1 (compiler inserts vmcnt wait on hv/cv here; loads were
    // issued a full iteration ago, covered by child_compute)
    commit_tiles(hbf[(n + 1) & 1], cbf[(n + 1) & 1], tid, hv, cv, htacc);
    if (n < NCH - 2) {  // issue child n+2, pinned here
      stage_load(h + ((size_t)(n + 2) * NB + row0) * 128, tid, hv);
      stage_load(C + ((size_t)(n + 2) * NB + row0) * 128, tid, cv);
      __builtin_amdgcn_sched_barrier(0);
    }
    WAITL0;                        // ds writes + reads retired
    __builtin_amdgcn_s_barrier();  // buffer n+1 visible; buffer n free next iter
  }

  // ---- peeled child 7 (buf 1) ----
  child_compute(hbf[1], cbf[1], uf0, uf1, afx, bf0, bf1, cl, g, cb, accc);
  __syncthreads();  // all reads done before h_tilde overwrite

  // ---- h_tilde -> bf16 swizzled tile in hbf[0] ----
  stage_write((u32x4v*)hbf[0], tid, htacc);
  __syncthreads();
  const u32x4v* ht = (const u32x4v*)hbf[0];
  float* ex = cbf[0];

  f32x4 pre[2][2], s4[4];

  // u = tanh(x@Wu + ht@Uu + bu)
#pragma unroll
  for (int m = 0; m < 2; ++m) { pre[m][0] = fz; pre[m][1] = fz; }
  gemm_g(xs, g_wt + 3 * 16384, cl, g, cb, pre);
  gemm_g(ht, g_wt + 7 * 16384, cl, g, cb, pre);
  f32x4 uF[2][2];
#pragma unroll
  for (int m = 0; m < 2; ++m)
#pragma unroll
    for (int nf = 0; nf < 2; ++nf) {
      float bv = nf ? bu1 : bu0;
#pragma unroll
      for (int r = 0; r < 4; ++r) uF[m][nf][r] = tanh_f(pre[m][nf][r] + bv);
    }

  // i gate -> c = i*u + accc
#pragma unroll
  for (int m = 0; m < 2; ++m) { pre[m][0] = fz; pre[m][1] = fz; }
  gemm_g(xs, g_wt + 0 * 16384, cl, g, cb, pre);
  gemm_g(ht, g_wt + 4 * 16384, cl, g, cb, pre);
  f32x4 cF[2][2], tF[2][2];
#pragma unroll
  for (int m = 0; m < 2; ++m)
#pragma unroll
    for (int nf = 0; nf < 2; ++nf) {
      float bv = nf ? bi1 : bi0;
#pragma unroll
      for (int r = 0; r < 4; ++r) {
        float cv2 = sigm(pre[m][nf][r] + bv) * uF[m][nf][r] + accc[m][nf][r];
        cF[m][nf][r] = cv2;
        tF[m][nf][r] = tanh_f(cv2);
      }
    }
  exch(ex, cF, g, cl, cb, tid, s4);
  float* outc = out + (size_t)NB * 128;
#pragma unroll
  for (int i = 0; i < 4; ++i)
    *(f32x4*)(outc + (size_t)(row0 + sr + i * 8) * 128 + sc) = s4[i];

  // o gate -> h_j
#pragma unroll
  for (int m = 0; m < 2; ++m) { pre[m][0] = fz; pre[m][1] = fz; }
  gemm_g(xs, g_wt + 2 * 16384, cl, g, cb, pre);
  gemm_g(ht, g_wt + 6 * 16384, cl, g, cb, pre);
  f32x4 hF[2][2];
#pragma unroll
  for (int m = 0; m < 2; ++m)
#pragma unroll
    for (int nf = 0; nf < 2; ++nf) {
      float bv = nf ? bo1 : bo0;
#pragma unroll
      for (int r = 0; r < 4; ++r)
        hF[m][nf][r] = sigm(pre[m][nf][r] + bv) * tF[m][nf][r];
    }
  exch(ex, hF, g, cl, cb, tid, s4);
#pragma unroll
  for (int i = 0; i < 4; ++i)
    *(f32x4*)(out + (size_t)(row0 + sr + i * 8) * 128 + sc) = s4[i];
}

extern "C" void kernel_launch(void* const* d_in, const int* in_sizes, int n_in,
                              void* d_out, int out_size, void* d_ws, size_t ws_size,
                              hipStream_t stream) {
  (void)in_sizes; (void)n_in; (void)out_size; (void)d_ws; (void)ws_size;
  const float* x = (const float*)d_in[0];
  const float* h = (const float*)d_in[1];
  const float* C = (const float*)d_in[2];

  prep_weights<<<8, 256, 0, stream>>>(
      (const float*)d_in[3], (const float*)d_in[4], (const float*)d_in[5],
      (const float*)d_in[6], (const float*)d_in[7], (const float*)d_in[8],
      (const float*)d_in[9], (const float*)d_in[10]);

  tree_lstm<<<NB / ROWS, 256, 0, stream>>>(
      x, h, C,
      (const float*)d_in[11], (const float*)d_in[12],
      (const float*)d_in[13], (const float*)d_in[14],
      (float*)d_out);
}